// Round 8
// baseline (234.717 us; speedup 1.0000x reference)
//
#include <hip/hip_runtime.h>
#include <math.h>

// ---------------------------------------------------------------------------
// LightweightEncoder, round 8: two launches.
//  k_fused01  : DMA-stage 19x68 x_init band -> h0 tile in LDS -> h1 out;
//               wave1: sigma (pre-barrier, overlapped with DMA) + sample conv
//               + pool1/pool2 (shuffles). Zeroes the completion counter.
//  k_fused23f : stage h1 band -> h2 tile in LDS -> f1 (LDS) -> L3 -> f2 (LDS)
//               -> final select + soft VQ + counts + hists for the block's
//               64x16 output region -> per-block partials -> last-block
//               reduce emits esti_cr + hist std. f1/f2 never touch HBM.
// ---------------------------------------------------------------------------

#define SENT -1e30f      // OOB sentinel: relu(inv*SENT+bb)==0 (pad-after-bnrelu)

// fused01 DMA layout: 19 rows x 68 floats (17 float4 slots), 323 slots/plane
#define DSTR 68
#define DPLANE 1292            // 323 * 4 floats

// staged h1 layout (fused23f) + mid-plane layout
#define SXSTR 72
#define SXCH  (19 * SXSTR)
#define H0STR 36
#define H0CH  (9 * H0STR)

__device__ __forceinline__ float featf(float h) { return 0.5f * (tanhf(h) + 1.0f); }

__device__ __forceinline__ void dma16(const float* g, float* l) {
    __builtin_amdgcn_global_load_lds((const __attribute__((address_space(1))) void*)g,
                                     (__attribute__((address_space(3))) void*)l,
                                     16, 0, 0);
}

// legacy staging (fused23f): 19 rows x 17 float4, SENT at OOB
__device__ __forceinline__ void stage19(const float* __restrict__ base,
                                        float* __restrict__ L,
                                        int gr0, int gc0, int S, int t) {
    #pragma unroll
    for (int p = 0; p < 2; p++) {
        int idx = t + 256 * p;
        if (idx < 323) {
            int lr = idx / 17;
            int s  = idx - lr * 17;
            int gr = gr0 + lr;
            int gc = gc0 + 4 * s;
            float4 v;
            if (gr >= 0 && gr < S && gc >= 0 && gc < S)
                v = *(const float4*)(base + (size_t)gr * S + gc);
            else { v.x = SENT; v.y = SENT; v.z = SENT; v.w = SENT; }
            *(float4*)&L[lr * SXSTR + 4 * s] = v;
        }
    }
}

// ---------------------------------------------------------------------------
// K0: fused ctx L0+L1 + sample + pools. grid = 8 b * 64 bandY * 16 tileX.
// ---------------------------------------------------------------------------
__global__ __launch_bounds__(256) void k_fused01(
    const float* __restrict__ xin,
    const float* __restrict__ sw_g, const float* __restrict__ sb,
    const float* __restrict__ ctxw, const float* __restrict__ ctxb,
    const float* __restrict__ bng, const float* __restrict__ bnb,
    const float* __restrict__ p1w, const float* __restrict__ p1b,
    const float* __restrict__ p2w, const float* __restrict__ p2b,
    float* __restrict__ outX, float* __restrict__ outH1,
    float* __restrict__ outP1, float* __restrict__ outP2,
    int* __restrict__ counter)
{
    __shared__ float sx[3 * DPLANE];   // raw x_init band, slot-linear
    __shared__ float sm[3 * H0CH];     // h0 tile (raw; SENT at pad positions)

    int t = threadIdx.x, bid = blockIdx.x;
    int tileX = bid & 15, bandY = (bid >> 4) & 63, b = bid >> 10;

    if (bid == 0 && t == 0) *counter = 0;

    int gr0 = bandY * 16 - 3;
    int gc0 = tileX * 64 - 4;

    // ---- DMA staging: wave-uniform LDS base + lane*16, per-lane global addr ----
    {
        int slot0 = t;               // p = 0
        int lr0 = slot0 / 17, cs0 = slot0 - 17 * lr0;
        int slot1 = t + 256;         // p = 1 (valid when t < 67)
        int lr1 = slot1 / 17, cs1 = slot1 - 17 * lr1;
        int grA = min(max(gr0 + lr0, 0), 1023);
        int gcA = min(max(gc0 + 4 * cs0, 0), 1020);
        int grB = min(max(gr0 + lr1, 0), 1023);
        int gcB = min(max(gc0 + 4 * cs1, 0), 1020);
        int offA = (grA << 10) + gcA;
        int offB = (grB << 10) + gcB;
        int wbase = t & 192;         // 64 * wave_id
        #pragma unroll
        for (int c = 0; c < 3; c++) {
            const float* plane = xin + ((size_t)(b * 3 + c) << 20);
            dma16(plane + offA, &sx[c * DPLANE + 4 * wbase]);
            if (t < 67) dma16(plane + offB, &sx[c * DPLANE + 4 * (256 + wbase)]);
        }
    }

    // ---- wave1: sigma BEFORE the barrier (overlaps the DMA in flight) ----
    float inv_sigma = 0.0f;
    if (t >= 64 && t < 128) {
        int tl = t - 64;
        float p00 = 0.f, p01 = 0.f, p02 = 0.f, p11 = 0.f, p12 = 0.f, p22 = 0.f;
        if (tl < 48) {
            float a0 = sw_g[tl], a1 = sw_g[48 + tl], a2 = sw_g[96 + tl];
            p00 = a0 * a0; p01 = a0 * a1; p02 = a0 * a2;
            p11 = a1 * a1; p12 = a1 * a2; p22 = a2 * a2;
        }
        #pragma unroll
        for (int off = 32; off > 0; off >>= 1) {
            p00 += __shfl_down(p00, off); p01 += __shfl_down(p01, off);
            p02 += __shfl_down(p02, off); p11 += __shfl_down(p11, off);
            p12 += __shfl_down(p12, off); p22 += __shfl_down(p22, off);
        }
        if (tl == 0) {
            float q = (p00 + p11 + p22) * (1.0f / 3.0f);
            float pp1 = p01 * p01 + p02 * p02 + p12 * p12;
            float pp2 = (p00 - q) * (p00 - q) + (p11 - q) * (p11 - q)
                      + (p22 - q) * (p22 - q) + 2.0f * pp1;
            float lam;
            if (pp2 < 1e-30f) lam = q;
            else {
                float pr = sqrtf(pp2 / 6.0f);
                float B00 = (p00 - q) / pr, B01 = p01 / pr, B02 = p02 / pr;
                float B11 = (p11 - q) / pr, B12 = p12 / pr, B22 = (p22 - q) / pr;
                float detB = B00 * (B11 * B22 - B12 * B12)
                           - B01 * (B01 * B22 - B12 * B02)
                           + B02 * (B01 * B12 - B11 * B02);
                float r = fminf(1.0f, fmaxf(-1.0f, 0.5f * detB));
                lam = q + 2.0f * pr * cosf(acosf(r) * (1.0f / 3.0f));
            }
            double G00 = p00, G01 = p01, G02 = p02, G11 = p11, G12 = p12, G22 = p22;
            double c2 = G00 + G11 + G22;
            double c1 = G00 * G11 - G01 * G01 + G00 * G22 - G02 * G02 + G11 * G22 - G12 * G12;
            double c0 = G00 * (G11 * G22 - G12 * G12) - G01 * (G01 * G22 - G12 * G02)
                      + G02 * (G01 * G12 - G11 * G02);
            double L = (double)lam;
            #pragma unroll
            for (int it = 0; it < 2; it++) {
                double pv = ((L - c2) * L + c1) * L - c0;
                double dv = (3.0 * L - 2.0 * c2) * L + c1;
                L -= pv / dv;
            }
            inv_sigma = (float)(1.0 / sqrt(L));
        }
        inv_sigma = __shfl(inv_sigma, 0);
    }
    __syncthreads();   // drains vmcnt -> DMA complete

    // ---- SENT fixup on edge blocks (block-uniform branch) ----
    if (tileX == 0 || bandY == 0) {
        float4 sv; sv.x = SENT; sv.y = SENT; sv.z = SENT; sv.w = SENT;
        if (bandY == 0 && t < 153) {      // rows 0..2 (global rows -3..-1)
            int c = t / 51, rem = t - 51 * c;
            int lr = rem / 17, cs = rem - 17 * lr;
            *(float4*)&sx[c * DPLANE + lr * DSTR + 4 * cs] = sv;
        }
        if (tileX == 0 && t >= 192 && t < 249) {   // col slot 0 (global cols -4..-1)
            int u = t - 192;
            int c = u / 19, lr = u - 19 * c;
            *(float4*)&sx[c * DPLANE + lr * DSTR] = sv;
        }
        __syncthreads();
    }

    // ---- L0: h0 tile 9x33 ----
    {
        float inv0[3], bb0[3];
        #pragma unroll
        for (int c = 0; c < 3; c++) { inv0[c] = bng[c] / sqrtf(1.001f); bb0[c] = bnb[c]; }
        #pragma unroll
        for (int p = 0; p < 2; p++) {
            int idx = t + 256 * p;
            if (idx < 297) {
                int lhy = idx / 33;
                int lhx = idx - 33 * lhy;
                bool oob = (bandY == 0 && lhy == 0) || (tileX == 0 && lhx == 0);
                float a0 = ctxb[0], a1 = ctxb[1], a2 = ctxb[2];
                #pragma unroll
                for (int c = 0; c < 3; c++) {
                    const float* basep = &sx[c * DPLANE + 2 * lhy * DSTR + 2 * lhx];
                    float inv = inv0[c], bb = bb0[c];
                    #pragma unroll
                    for (int kh = 0; kh < 3; kh++) {
                        float2 c0 = *(const float2*)(basep + kh * DSTR);
                        float2 c1 = *(const float2*)(basep + kh * DSTR + 2);
                        float t0 = fmaxf(fmaf(inv, c0.y, bb), 0.0f);
                        float t1 = fmaxf(fmaf(inv, c1.x, bb), 0.0f);
                        float t2 = fmaxf(fmaf(inv, c1.y, bb), 0.0f);
                        int wi = c * 9 + kh * 3;
                        a0 = fmaf(ctxw[wi], t0, a0); a0 = fmaf(ctxw[wi + 1], t1, a0); a0 = fmaf(ctxw[wi + 2], t2, a0);
                        a1 = fmaf(ctxw[27 + wi], t0, a1); a1 = fmaf(ctxw[28 + wi], t1, a1); a1 = fmaf(ctxw[29 + wi], t2, a1);
                        a2 = fmaf(ctxw[54 + wi], t0, a2); a2 = fmaf(ctxw[55 + wi], t1, a2); a2 = fmaf(ctxw[56 + wi], t2, a2);
                    }
                }
                int o = lhy * H0STR + lhx;
                if (oob) { a0 = SENT; a1 = SENT; a2 = SENT; }
                sm[o] = a0; sm[H0CH + o] = a1; sm[2 * H0CH + o] = a2;
            }
        }
    }
    __syncthreads();

    if (t < 64) {
        // ---- wave0: L1 conv -> h1 (16x4 tile) ----
        int lx = t & 15, ly = t >> 4;
        const float* w1c = ctxw + 81;
        float a0 = ctxb[3], a1 = ctxb[4], a2 = ctxb[5];
        #pragma unroll
        for (int c = 0; c < 3; c++) {
            float inv = bng[3 + c] / sqrtf(1.001f), bb = bnb[3 + c];
            const float* mb = &sm[c * H0CH + 2 * ly * H0STR + 2 * lx];
            #pragma unroll
            for (int kh = 0; kh < 3; kh++) {
                float2 c0 = *(const float2*)(mb + kh * H0STR);
                float c2v = mb[kh * H0STR + 2];
                float t0 = fmaxf(fmaf(inv, c0.x, bb), 0.0f);
                float t1 = fmaxf(fmaf(inv, c0.y, bb), 0.0f);
                float t2 = fmaxf(fmaf(inv, c2v, bb), 0.0f);
                int wi = c * 9 + kh * 3;
                a0 = fmaf(w1c[wi], t0, a0); a0 = fmaf(w1c[wi + 1], t1, a0); a0 = fmaf(w1c[wi + 2], t2, a0);
                a1 = fmaf(w1c[27 + wi], t0, a1); a1 = fmaf(w1c[28 + wi], t1, a1); a1 = fmaf(w1c[29 + wi], t2, a1);
                a2 = fmaf(w1c[54 + wi], t0, a2); a2 = fmaf(w1c[55 + wi], t1, a2); a2 = fmaf(w1c[56 + wi], t2, a2);
            }
        }
        unsigned o = (unsigned)(b * 3) * 65536u + (unsigned)(bandY * 4 + ly) * 256u + tileX * 16 + lx;
        outH1[o] = a0; outH1[o + 65536u] = a1; outH1[o + 131072u] = a2;
    } else if (t < 128) {
        int tl = t - 64;
        // ---- wave1: sample conv (uses pre-computed inv_sigma) ----
        int xl = tl & 15, yl = tl >> 4;
        float4 r[3][4];
        #pragma unroll
        for (int c = 0; c < 3; c++)
            #pragma unroll
            for (int kh = 0; kh < 4; kh++)
                r[c][kh] = *(const float4*)&sx[c * DPLANE + (4 * yl + 3 + kh) * DSTR + 4 * xl + 4];
        float s0 = 0.f, s1 = 0.f, s2 = 0.f;
        #pragma unroll
        for (int c = 0; c < 3; c++)
            #pragma unroll
            for (int kh = 0; kh < 4; kh++) {
                float4 vv = r[c][kh];
                const float* w0 = &sw_g[(0 * 3 + c) * 16 + kh * 4];
                const float* w1 = &sw_g[(1 * 3 + c) * 16 + kh * 4];
                const float* w2 = &sw_g[(2 * 3 + c) * 16 + kh * 4];
                s0 += w0[0] * vv.x + w0[1] * vv.y + w0[2] * vv.z + w0[3] * vv.w;
                s1 += w1[0] * vv.x + w1[1] * vv.y + w1[2] * vv.z + w1[3] * vv.w;
                s2 += w2[0] * vv.x + w2[1] * vv.y + w2[2] * vv.z + w2[3] * vv.w;
            }
        float x0 = fmaf(s0, inv_sigma, sb[0]);
        float x1 = fmaf(s1, inv_sigma, sb[1]);
        float x2 = fmaf(s2, inv_sigma, sb[2]);
        unsigned o = (unsigned)(b * 3) * 65536u + (unsigned)(bandY * 4 + yl) * 256u + tileX * 16 + xl;
        outX[o] = x0; outX[o + 65536u] = x1; outX[o + 131072u] = x2;

        // ---- pool1 via shuffles ----
        int sl = 2 * (tl & 7) + 32 * ((tl >> 3) & 1);
        float q0 = p1b[0], q1 = p1b[1], q2 = p1b[2];
        #pragma unroll
        for (int dy = 0; dy < 2; dy++)
            #pragma unroll
            for (int dx = 0; dx < 2; dx++) {
                int src = sl + dx + 16 * dy;
                float vx0 = __shfl(x0, src);
                float vx1 = __shfl(x1, src);
                float vx2 = __shfl(x2, src);
                int wi = dy * 2 + dx;
                q0 = fmaf(p1w[wi], vx0, q0); q0 = fmaf(p1w[4 + wi],  vx1, q0); q0 = fmaf(p1w[8 + wi],  vx2, q0);
                q1 = fmaf(p1w[12 + wi], vx0, q1); q1 = fmaf(p1w[16 + wi], vx1, q1); q1 = fmaf(p1w[20 + wi], vx2, q1);
                q2 = fmaf(p1w[24 + wi], vx0, q2); q2 = fmaf(p1w[28 + wi], vx1, q2); q2 = fmaf(p1w[32 + wi], vx2, q2);
            }
        if (tl < 16) {
            int px = tl & 7, py = tl >> 3;
            unsigned op = (unsigned)(b * 3) * 16384u + (unsigned)(bandY * 2 + py) * 128u + tileX * 8 + px;
            outP1[op] = q0; outP1[op + 16384u] = q1; outP1[op + 32768u] = q2;
        }

        // ---- pool2 via shuffles ----
        int s2l = 2 * (tl & 3);
        float r0 = p2b[0], r1 = p2b[1], r2 = p2b[2];
        #pragma unroll
        for (int dy = 0; dy < 2; dy++)
            #pragma unroll
            for (int dx = 0; dx < 2; dx++) {
                int src = s2l + dx + 8 * dy;
                float vq0 = __shfl(q0, src);
                float vq1 = __shfl(q1, src);
                float vq2 = __shfl(q2, src);
                int wi = dy * 2 + dx;
                r0 = fmaf(p2w[wi], vq0, r0); r0 = fmaf(p2w[4 + wi],  vq1, r0); r0 = fmaf(p2w[8 + wi],  vq2, r0);
                r1 = fmaf(p2w[12 + wi], vq0, r1); r1 = fmaf(p2w[16 + wi], vq1, r1); r1 = fmaf(p2w[20 + wi], vq2, r1);
                r2 = fmaf(p2w[24 + wi], vq0, r2); r2 = fmaf(p2w[28 + wi], vq1, r2); r2 = fmaf(p2w[32 + wi], vq2, r2);
            }
        if (tl < 4) {
            unsigned op = (unsigned)(b * 3) * 4096u + (unsigned)bandY * 64u + tileX * 4 + tl;
            outP2[op] = r0; outP2[op + 4096u] = r1; outP2[op + 8192u] = r2;
        }
    }
}

// ---------------------------------------------------------------------------
// K1: fused ctx L2+L3 + final + reduce. grid = 8 b * 16 bandY * 4 tileX = 512.
// Block covers x/out region rows 16*bandY..+15, cols 64*tileX..+63 (all 3 ch).
// ---------------------------------------------------------------------------
__device__ __forceinline__ int argmin8(float v, const float* __restrict__ sc) {
    float best = 1e30f; int ki = 0;
    #pragma unroll
    for (int k = 0; k < 8; k++) {
        float df = v - sc[k]; float dk = df * df;
        if (dk < best) { best = dk; ki = k; }
    }
    return ki;
}

__global__ __launch_bounds__(256) void k_fused23f(
    const float* __restrict__ h1, const float* __restrict__ x,
    const float* __restrict__ p1, const float* __restrict__ p2,
    const float* __restrict__ thresh, const float* __restrict__ centers,
    const float* __restrict__ ctxw, const float* __restrict__ ctxb,
    const float* __restrict__ bng, const float* __restrict__ bnb,
    float* __restrict__ out, int* __restrict__ partials,
    int* __restrict__ counter, float* __restrict__ out2)
{
    __shared__ float sx[3 * SXCH];     // staged h1 band
    __shared__ float sm[3 * H0CH];     // h2 tile (raw; SENT pads)
    __shared__ float sf1[3 * 256];     // feat(h2) interior [3][8][32]
    __shared__ float sf2[3 * 64];      // feat(h3) [3][4][16]
    __shared__ int sh[4 * 12];
    __shared__ int accs[12];
    __shared__ bool s_last;

    int t = threadIdx.x, bid = blockIdx.x;
    int tileX = bid & 3, bandY = (bid >> 2) & 15, b = bid >> 6;
    int lane = t & 63;
    int* shW = &sh[12 * (t >> 6)];
    if (lane < 12) shW[lane] = 0;
    if (t == 0) s_last = false;

    int gr0 = bandY * 16 - 3;
    int gc0 = tileX * 64 - 4;
    #pragma unroll
    for (int c = 0; c < 3; c++)
        stage19(h1 + (size_t)(b * 3 + c) * 65536, &sx[c * SXCH], gr0, gc0, 256, t);
    __syncthreads();

    // ---- L2: h2 tile 9x33 -> sm; feat(h2) interior 8x32 -> sf1 ----
    {
        const float* w2c = ctxw + 162;
        float inv2[3], bb2[3];
        #pragma unroll
        for (int c = 0; c < 3; c++) { inv2[c] = bng[6 + c] / sqrtf(1.001f); bb2[c] = bnb[6 + c]; }
        #pragma unroll
        for (int p = 0; p < 2; p++) {
            int idx = t + 256 * p;
            if (idx < 297) {
                int lhy = idx / 33;
                int lhx = idx - 33 * lhy;
                bool oob = (bandY == 0 && lhy == 0) || (tileX == 0 && lhx == 0);
                float a0 = ctxb[6], a1 = ctxb[7], a2 = ctxb[8];
                #pragma unroll
                for (int c = 0; c < 3; c++) {
                    const float* basep = &sx[c * SXCH + 2 * lhy * SXSTR + 2 * lhx];
                    float inv = inv2[c], bb = bb2[c];
                    #pragma unroll
                    for (int kh = 0; kh < 3; kh++) {
                        float2 c0 = *(const float2*)(basep + kh * SXSTR);
                        float2 c1 = *(const float2*)(basep + kh * SXSTR + 2);
                        float t0 = fmaxf(fmaf(inv, c0.y, bb), 0.0f);
                        float t1 = fmaxf(fmaf(inv, c1.x, bb), 0.0f);
                        float t2 = fmaxf(fmaf(inv, c1.y, bb), 0.0f);
                        int wi = c * 9 + kh * 3;
                        a0 = fmaf(w2c[wi], t0, a0); a0 = fmaf(w2c[wi + 1], t1, a0); a0 = fmaf(w2c[wi + 2], t2, a0);
                        a1 = fmaf(w2c[27 + wi], t0, a1); a1 = fmaf(w2c[28 + wi], t1, a1); a1 = fmaf(w2c[29 + wi], t2, a1);
                        a2 = fmaf(w2c[54 + wi], t0, a2); a2 = fmaf(w2c[55 + wi], t1, a2); a2 = fmaf(w2c[56 + wi], t2, a2);
                    }
                }
                int o = lhy * H0STR + lhx;
                if (lhy >= 1 && lhx >= 1) {
                    int fo = (lhy - 1) * 32 + (lhx - 1);
                    sf1[fo] = featf(a0); sf1[256 + fo] = featf(a1); sf1[512 + fo] = featf(a2);
                }
                if (oob) { a0 = SENT; a1 = SENT; a2 = SENT; }
                sm[o] = a0; sm[H0CH + o] = a1; sm[2 * H0CH + o] = a2;
            }
        }
    }
    __syncthreads();

    // ---- L3 -> f2 (16x4 tile) -> sf2 ----
    if (t < 64) {
        int lx = t & 15, ly = t >> 4;
        const float* w3c = ctxw + 243;
        float a0 = ctxb[9], a1 = ctxb[10], a2 = ctxb[11];
        #pragma unroll
        for (int c = 0; c < 3; c++) {
            float inv = bng[9 + c] / sqrtf(1.001f), bb = bnb[9 + c];
            const float* mb = &sm[c * H0CH + 2 * ly * H0STR + 2 * lx];
            #pragma unroll
            for (int kh = 0; kh < 3; kh++) {
                float2 c0 = *(const float2*)(mb + kh * H0STR);
                float c2v = mb[kh * H0STR + 2];
                float t0 = fmaxf(fmaf(inv, c0.x, bb), 0.0f);
                float t1 = fmaxf(fmaf(inv, c0.y, bb), 0.0f);
                float t2 = fmaxf(fmaf(inv, c2v, bb), 0.0f);
                int wi = c * 9 + kh * 3;
                a0 = fmaf(w3c[wi], t0, a0); a0 = fmaf(w3c[wi + 1], t1, a0); a0 = fmaf(w3c[wi + 2], t2, a0);
                a1 = fmaf(w3c[27 + wi], t0, a1); a1 = fmaf(w3c[28 + wi], t1, a1); a1 = fmaf(w3c[29 + wi], t2, a1);
                a2 = fmaf(w3c[54 + wi], t0, a2); a2 = fmaf(w3c[55 + wi], t1, a2); a2 = fmaf(w3c[56 + wi], t2, a2);
            }
        }
        sf2[t] = featf(a0); sf2[64 + t] = featf(a1); sf2[128 + t] = featf(a2);
    }
    __syncthreads();

    // ---- final phase: 64x16x3 region, 12 px/thread ----
    float sc[8];
    #pragma unroll
    for (int k = 0; k < 8; k++) sc[k] = centers[k];
    float th1 = thresh[0], th2 = thresh[1];
    int y0 = bandY * 16, x0r = tileX * 64;
    int c0n = 0, c1n = 0, c2n = 0;

    #pragma unroll
    for (int k12 = 0; k12 < 12; k12++) {
        int idx = t + 256 * k12;
        int c = idx >> 10;
        int rem = idx & 1023;
        int ly2 = rem >> 6, lx2 = rem & 63;
        int y = y0 + ly2, xg = x0r + lx2;
        unsigned pc = (unsigned)(b * 3 + c);

        float f1v = sf1[(c << 8) + ((ly2 >> 1) << 5) + (lx2 >> 1)];
        float f2v = sf2[(c << 6) + ((ly2 >> 2) << 4) + (lx2 >> 2)];
        float p1v = p1[pc * 16384u + (unsigned)(((y >> 1) << 7) + (xg >> 1))];
        float p2v = p2[pc * 4096u + (unsigned)(((y >> 2) << 6) + (xg >> 2))];
        float xv  = x[pc * 65536u + (unsigned)((y << 8) + xg)];

        bool cond2 = f2v < th2;
        bool cond1 = (!cond2) && (f1v < th1);
        bool cond0 = !(cond1 || cond2);
        float xq = cond2 ? p2v : (cond1 ? p1v : xv);

        float d[8]; float dmin = 1e30f;
        #pragma unroll
        for (int k = 0; k < 8; k++) { float df = xq - sc[k]; d[k] = df * df; dmin = fminf(dmin, d[k]); }
        float se = 0.f, sn = 0.f;
        #pragma unroll
        for (int k = 0; k < 8; k++) { float e = __expf(dmin - d[k]); se += e; sn = fmaf(sc[k], e, sn); }
        out[pc * 65536u + (unsigned)((y << 8) + xg)] = sn / se;

        c0n += cond0; c1n += cond1; c2n += cond2;

        bool doM1 = ((y & 1) == 0) && ((xg & 1) == 0);
        bool doM2 = ((y & 3) == 0) && ((xg & 3) == 0);
        if (cond0) atomicAdd(&shW[argmin8(xv, sc)], 1);
        if (doM1 && (f2v >= th2) && (f1v < th1)) atomicAdd(&shW[argmin8(p1v, sc)], 1);
        if (doM2 && cond2) atomicAdd(&shW[argmin8(p2v, sc)], 1);
    }
    #pragma unroll
    for (int off = 32; off > 0; off >>= 1) {
        c0n += __shfl_down(c0n, off);
        c1n += __shfl_down(c1n, off);
        c2n += __shfl_down(c2n, off);
    }
    if (lane == 0) { atomicAdd(&shW[8], c0n); atomicAdd(&shW[9], c1n); atomicAdd(&shW[10], c2n); }
    __syncthreads();
    if (t < 12)
        partials[bid * 12 + t] = sh[t] + sh[12 + t] + sh[24 + t] + sh[36 + t];
    __syncthreads();
    __threadfence();
    if (t == 0) {
        unsigned done = atomicAdd((unsigned*)counter, 1u);
        s_last = (done == 511u);
    }
    __syncthreads();

    // ---- last block: reduce 512x12 partials -> scalars ----
    if (s_last) {
        if (t < 12) accs[t] = 0;
        __syncthreads();
        int s[12];
        #pragma unroll
        for (int k = 0; k < 12; k++) s[k] = 0;
        for (int r = t; r < 512; r += 256) {
            int* row = partials + r * 12;
            #pragma unroll
            for (int k = 0; k < 12; k++) s[k] += atomicAdd(&row[k], 0);
        }
        #pragma unroll
        for (int k = 0; k < 12; k++) {
            #pragma unroll
            for (int off = 32; off > 0; off >>= 1) s[k] += __shfl_down(s[k], off);
        }
        if (lane == 0) {
            #pragma unroll
            for (int k = 0; k < 12; k++) if (s[k]) atomicAdd(&accs[k], s[k]);
        }
        __syncthreads();
        if (t == 0) {
            float cnt0 = (float)accs[8], cnt1 = (float)accs[9], cnt2 = (float)accs[10];
            float esti = cnt0 + cnt1 * 0.25f + cnt2 * 0.0625f;
            float cr = (1.0f / 16.0f) * esti / (256.0f * 256.0f * 3.0f * 8.0f);
            float cs[8]; float tot = 0.0f;
            #pragma unroll
            for (int k = 0; k < 8; k++) { cs[k] = (float)accs[k]; tot += cs[k]; }
            float mean = 0.0f;
            #pragma unroll
            for (int k = 0; k < 8; k++) { cs[k] /= tot; mean += cs[k]; }
            mean *= 0.125f;
            float var = 0.0f;
            #pragma unroll
            for (int k = 0; k < 8; k++) { float df = cs[k] - mean; var += df * df; }
            var *= (1.0f / 7.0f);
            out2[0] = cr;
            out2[1] = sqrtf(var);
        }
    }
}

extern "C" void kernel_launch(void* const* d_in, const int* in_sizes, int n_in,
                              void* d_out, int out_size, void* d_ws, size_t ws_size,
                              hipStream_t stream) {
    const float* x_init   = (const float*)d_in[0];
    const float* thresh   = (const float*)d_in[1];
    const float* sample_w = (const float*)d_in[2];
    const float* sample_b = (const float*)d_in[3];
    const float* centers  = (const float*)d_in[4];
    const float* pool1_w  = (const float*)d_in[5];
    const float* pool1_b  = (const float*)d_in[6];
    const float* pool2_w  = (const float*)d_in[7];
    const float* pool2_b  = (const float*)d_in[8];
    const float* ctx_w    = (const float*)d_in[9];
    const float* ctx_b    = (const float*)d_in[10];
    const float* bn_g     = (const float*)d_in[11];
    const float* bn_b     = (const float*)d_in[12];
    float* out = (float*)d_out;

    float* wsf      = (float*)d_ws;
    int*   partials = (int*)wsf;               // [512][12] ints
    int*   counter  = partials + 6144;         // completion counter
    float* bufX     = wsf + 32768;             // [8,3,256,256]
    float* bufH1    = bufX  + 1572864;         // [8,3,256,256]
    float* bufP1    = bufH1 + 1572864;         // [8,3,128,128]
    float* bufP2    = bufP1 + 393216;          // [8,3,64,64]

    k_fused01<<<8192, 256, 0, stream>>>(x_init, sample_w, sample_b,
                                        ctx_w, ctx_b, bn_g, bn_b,
                                        pool1_w, pool1_b, pool2_w, pool2_b,
                                        bufX, bufH1, bufP1, bufP2, counter);
    k_fused23f<<<512, 256, 0, stream>>>(bufH1, bufX, bufP1, bufP2,
                                        thresh, centers,
                                        ctx_w, ctx_b, bn_g, bn_b,
                                        out, partials, counter, out + 1572864);
}

// Round 9
// 203.676 us; speedup vs baseline: 1.1524x; 1.1524x over previous
//
#include <hip/hip_runtime.h>
#include <math.h>

// ---------------------------------------------------------------------------
// LightweightEncoder, round 9: R7 structure (proven 206.5) + sigma overlapped
// with DMA from R8. Four launches.
//  k_fused01 : DMA-stage 19x68 x_init band -> h0 tile in LDS -> h1 out;
//              wave1: sigma (pre-barrier, overlaps DMA) + sample conv +
//              pool1/pool2 (shuffles).
//  k_fused23 : stage h1 band -> h2 tile in LDS -> f1/f2 out (HBM, small).
//  k_final   : select + soft VQ + counts + hists -> per-block partials
//              (2048 blocks for latency hiding -- R8 showed 512 is too few).
//  k_reduce  : 1 block; scalars.
// ---------------------------------------------------------------------------

#define SENT -1e30f      // OOB sentinel: relu(inv*SENT+bb)==0 (pad-after-bnrelu)

// fused01 DMA layout: 19 rows x 68 floats (17 float4 slots), 323 slots/plane
#define DSTR 68
#define DPLANE 1292            // 323 * 4 floats

// fused23 legacy layout
#define SXSTR 72
#define SXCH  (19 * SXSTR)
#define H0STR 36
#define H0CH  (9 * H0STR)

__device__ __forceinline__ float featf(float h) { return 0.5f * (tanhf(h) + 1.0f); }

__device__ __forceinline__ void dma16(const float* g, float* l) {
    __builtin_amdgcn_global_load_lds((const __attribute__((address_space(1))) void*)g,
                                     (__attribute__((address_space(3))) void*)l,
                                     16, 0, 0);
}

// legacy staging for fused23
__device__ __forceinline__ void stage19(const float* __restrict__ base,
                                        float* __restrict__ L,
                                        int gr0, int gc0, int S, int t) {
    #pragma unroll
    for (int p = 0; p < 2; p++) {
        int idx = t + 256 * p;
        if (idx < 323) {
            int lr = idx / 17;
            int s  = idx - lr * 17;
            int gr = gr0 + lr;
            int gc = gc0 + 4 * s;
            float4 v;
            if (gr >= 0 && gr < S && gc >= 0 && gc < S)
                v = *(const float4*)(base + (size_t)gr * S + gc);
            else { v.x = SENT; v.y = SENT; v.z = SENT; v.w = SENT; }
            *(float4*)&L[lr * SXSTR + 4 * s] = v;
        }
    }
}

// ---------------------------------------------------------------------------
// K0: fused ctx L0+L1 + sample + pools. grid = 8 b * 64 bandY * 16 tileX.
// ---------------------------------------------------------------------------
__global__ __launch_bounds__(256) void k_fused01(
    const float* __restrict__ xin,
    const float* __restrict__ sw_g, const float* __restrict__ sb,
    const float* __restrict__ ctxw, const float* __restrict__ ctxb,
    const float* __restrict__ bng, const float* __restrict__ bnb,
    const float* __restrict__ p1w, const float* __restrict__ p1b,
    const float* __restrict__ p2w, const float* __restrict__ p2b,
    float* __restrict__ outX, float* __restrict__ outH1,
    float* __restrict__ outP1, float* __restrict__ outP2)
{
    __shared__ float sx[3 * DPLANE];   // raw x_init band, slot-linear
    __shared__ float sm[3 * H0CH];     // h0 tile (raw; SENT at pad positions)

    int t = threadIdx.x, bid = blockIdx.x;
    int tileX = bid & 15, bandY = (bid >> 4) & 63, b = bid >> 10;

    int gr0 = bandY * 16 - 3;
    int gc0 = tileX * 64 - 4;

    // ---- DMA staging: wave-uniform LDS base + lane*16, per-lane global addr ----
    {
        int slot0 = t;               // p = 0
        int lr0 = slot0 / 17, cs0 = slot0 - 17 * lr0;
        int slot1 = t + 256;         // p = 1 (valid when t < 67)
        int lr1 = slot1 / 17, cs1 = slot1 - 17 * lr1;
        int grA = min(max(gr0 + lr0, 0), 1023);
        int gcA = min(max(gc0 + 4 * cs0, 0), 1020);
        int grB = min(max(gr0 + lr1, 0), 1023);
        int gcB = min(max(gc0 + 4 * cs1, 0), 1020);
        int offA = (grA << 10) + gcA;
        int offB = (grB << 10) + gcB;
        int wbase = t & 192;         // 64 * wave_id
        #pragma unroll
        for (int c = 0; c < 3; c++) {
            const float* plane = xin + ((size_t)(b * 3 + c) << 20);
            dma16(plane + offA, &sx[c * DPLANE + 4 * wbase]);
            if (t < 67) dma16(plane + offB, &sx[c * DPLANE + 4 * (256 + wbase)]);
        }
    }

    // ---- wave1: sigma BEFORE the barrier (overlaps the DMA in flight) ----
    float inv_sigma = 0.0f;
    if (t >= 64 && t < 128) {
        int tl = t - 64;
        float p00 = 0.f, p01 = 0.f, p02 = 0.f, p11 = 0.f, p12 = 0.f, p22 = 0.f;
        if (tl < 48) {
            float a0 = sw_g[tl], a1 = sw_g[48 + tl], a2 = sw_g[96 + tl];
            p00 = a0 * a0; p01 = a0 * a1; p02 = a0 * a2;
            p11 = a1 * a1; p12 = a1 * a2; p22 = a2 * a2;
        }
        #pragma unroll
        for (int off = 32; off > 0; off >>= 1) {
            p00 += __shfl_down(p00, off); p01 += __shfl_down(p01, off);
            p02 += __shfl_down(p02, off); p11 += __shfl_down(p11, off);
            p12 += __shfl_down(p12, off); p22 += __shfl_down(p22, off);
        }
        if (tl == 0) {
            float q = (p00 + p11 + p22) * (1.0f / 3.0f);
            float pp1 = p01 * p01 + p02 * p02 + p12 * p12;
            float pp2 = (p00 - q) * (p00 - q) + (p11 - q) * (p11 - q)
                      + (p22 - q) * (p22 - q) + 2.0f * pp1;
            float lam;
            if (pp2 < 1e-30f) lam = q;
            else {
                float pr = sqrtf(pp2 / 6.0f);
                float B00 = (p00 - q) / pr, B01 = p01 / pr, B02 = p02 / pr;
                float B11 = (p11 - q) / pr, B12 = p12 / pr, B22 = (p22 - q) / pr;
                float detB = B00 * (B11 * B22 - B12 * B12)
                           - B01 * (B01 * B22 - B12 * B02)
                           + B02 * (B01 * B12 - B11 * B02);
                float r = fminf(1.0f, fmaxf(-1.0f, 0.5f * detB));
                lam = q + 2.0f * pr * cosf(acosf(r) * (1.0f / 3.0f));
            }
            double G00 = p00, G01 = p01, G02 = p02, G11 = p11, G12 = p12, G22 = p22;
            double c2 = G00 + G11 + G22;
            double c1 = G00 * G11 - G01 * G01 + G00 * G22 - G02 * G02 + G11 * G22 - G12 * G12;
            double c0 = G00 * (G11 * G22 - G12 * G12) - G01 * (G01 * G22 - G12 * G02)
                      + G02 * (G01 * G12 - G11 * G02);
            double L = (double)lam;
            #pragma unroll
            for (int it = 0; it < 2; it++) {
                double pv = ((L - c2) * L + c1) * L - c0;
                double dv = (3.0 * L - 2.0 * c2) * L + c1;
                L -= pv / dv;
            }
            inv_sigma = (float)(1.0 / sqrt(L));
        }
        inv_sigma = __shfl(inv_sigma, 0);
    }
    __syncthreads();   // drains vmcnt -> DMA complete

    // ---- SENT fixup on edge blocks (block-uniform branch) ----
    if (tileX == 0 || bandY == 0) {
        float4 sv; sv.x = SENT; sv.y = SENT; sv.z = SENT; sv.w = SENT;
        if (bandY == 0 && t < 153) {      // rows 0..2 (global rows -3..-1)
            int c = t / 51, rem = t - 51 * c;
            int lr = rem / 17, cs = rem - 17 * lr;
            *(float4*)&sx[c * DPLANE + lr * DSTR + 4 * cs] = sv;
        }
        if (tileX == 0 && t >= 192 && t < 249) {   // col slot 0 (global cols -4..-1)
            int u = t - 192;
            int c = u / 19, lr = u - 19 * c;
            *(float4*)&sx[c * DPLANE + lr * DSTR] = sv;
        }
        __syncthreads();
    }

    // ---- L0: h0 tile 9x33 ----
    {
        float inv0[3], bb0[3];
        #pragma unroll
        for (int c = 0; c < 3; c++) { inv0[c] = bng[c] / sqrtf(1.001f); bb0[c] = bnb[c]; }
        #pragma unroll
        for (int p = 0; p < 2; p++) {
            int idx = t + 256 * p;
            if (idx < 297) {
                int lhy = idx / 33;
                int lhx = idx - 33 * lhy;
                bool oob = (bandY == 0 && lhy == 0) || (tileX == 0 && lhx == 0);
                float a0 = ctxb[0], a1 = ctxb[1], a2 = ctxb[2];
                #pragma unroll
                for (int c = 0; c < 3; c++) {
                    const float* basep = &sx[c * DPLANE + 2 * lhy * DSTR + 2 * lhx];
                    float inv = inv0[c], bb = bb0[c];
                    #pragma unroll
                    for (int kh = 0; kh < 3; kh++) {
                        float2 c0 = *(const float2*)(basep + kh * DSTR);
                        float2 c1 = *(const float2*)(basep + kh * DSTR + 2);
                        float t0 = fmaxf(fmaf(inv, c0.y, bb), 0.0f);
                        float t1 = fmaxf(fmaf(inv, c1.x, bb), 0.0f);
                        float t2 = fmaxf(fmaf(inv, c1.y, bb), 0.0f);
                        int wi = c * 9 + kh * 3;
                        a0 = fmaf(ctxw[wi], t0, a0); a0 = fmaf(ctxw[wi + 1], t1, a0); a0 = fmaf(ctxw[wi + 2], t2, a0);
                        a1 = fmaf(ctxw[27 + wi], t0, a1); a1 = fmaf(ctxw[28 + wi], t1, a1); a1 = fmaf(ctxw[29 + wi], t2, a1);
                        a2 = fmaf(ctxw[54 + wi], t0, a2); a2 = fmaf(ctxw[55 + wi], t1, a2); a2 = fmaf(ctxw[56 + wi], t2, a2);
                    }
                }
                int o = lhy * H0STR + lhx;
                if (oob) { a0 = SENT; a1 = SENT; a2 = SENT; }
                sm[o] = a0; sm[H0CH + o] = a1; sm[2 * H0CH + o] = a2;
            }
        }
    }
    __syncthreads();

    if (t < 64) {
        // ---- wave0: L1 conv -> h1 (16x4 tile) ----
        int lx = t & 15, ly = t >> 4;
        const float* w1c = ctxw + 81;
        float a0 = ctxb[3], a1 = ctxb[4], a2 = ctxb[5];
        #pragma unroll
        for (int c = 0; c < 3; c++) {
            float inv = bng[3 + c] / sqrtf(1.001f), bb = bnb[3 + c];
            const float* mb = &sm[c * H0CH + 2 * ly * H0STR + 2 * lx];
            #pragma unroll
            for (int kh = 0; kh < 3; kh++) {
                float2 c0 = *(const float2*)(mb + kh * H0STR);
                float c2v = mb[kh * H0STR + 2];
                float t0 = fmaxf(fmaf(inv, c0.x, bb), 0.0f);
                float t1 = fmaxf(fmaf(inv, c0.y, bb), 0.0f);
                float t2 = fmaxf(fmaf(inv, c2v, bb), 0.0f);
                int wi = c * 9 + kh * 3;
                a0 = fmaf(w1c[wi], t0, a0); a0 = fmaf(w1c[wi + 1], t1, a0); a0 = fmaf(w1c[wi + 2], t2, a0);
                a1 = fmaf(w1c[27 + wi], t0, a1); a1 = fmaf(w1c[28 + wi], t1, a1); a1 = fmaf(w1c[29 + wi], t2, a1);
                a2 = fmaf(w1c[54 + wi], t0, a2); a2 = fmaf(w1c[55 + wi], t1, a2); a2 = fmaf(w1c[56 + wi], t2, a2);
            }
        }
        unsigned o = (unsigned)(b * 3) * 65536u + (unsigned)(bandY * 4 + ly) * 256u + tileX * 16 + lx;
        outH1[o] = a0; outH1[o + 65536u] = a1; outH1[o + 131072u] = a2;
    } else if (t < 128) {
        int tl = t - 64;
        // ---- wave1: sample conv (uses pre-computed inv_sigma) ----
        int xl = tl & 15, yl = tl >> 4;
        float4 r[3][4];
        #pragma unroll
        for (int c = 0; c < 3; c++)
            #pragma unroll
            for (int kh = 0; kh < 4; kh++)
                r[c][kh] = *(const float4*)&sx[c * DPLANE + (4 * yl + 3 + kh) * DSTR + 4 * xl + 4];
        float s0 = 0.f, s1 = 0.f, s2 = 0.f;
        #pragma unroll
        for (int c = 0; c < 3; c++)
            #pragma unroll
            for (int kh = 0; kh < 4; kh++) {
                float4 vv = r[c][kh];
                const float* w0 = &sw_g[(0 * 3 + c) * 16 + kh * 4];
                const float* w1 = &sw_g[(1 * 3 + c) * 16 + kh * 4];
                const float* w2 = &sw_g[(2 * 3 + c) * 16 + kh * 4];
                s0 += w0[0] * vv.x + w0[1] * vv.y + w0[2] * vv.z + w0[3] * vv.w;
                s1 += w1[0] * vv.x + w1[1] * vv.y + w1[2] * vv.z + w1[3] * vv.w;
                s2 += w2[0] * vv.x + w2[1] * vv.y + w2[2] * vv.z + w2[3] * vv.w;
            }
        float x0 = fmaf(s0, inv_sigma, sb[0]);
        float x1 = fmaf(s1, inv_sigma, sb[1]);
        float x2 = fmaf(s2, inv_sigma, sb[2]);
        unsigned o = (unsigned)(b * 3) * 65536u + (unsigned)(bandY * 4 + yl) * 256u + tileX * 16 + xl;
        outX[o] = x0; outX[o + 65536u] = x1; outX[o + 131072u] = x2;

        // ---- pool1 via shuffles ----
        int sl = 2 * (tl & 7) + 32 * ((tl >> 3) & 1);
        float q0 = p1b[0], q1 = p1b[1], q2 = p1b[2];
        #pragma unroll
        for (int dy = 0; dy < 2; dy++)
            #pragma unroll
            for (int dx = 0; dx < 2; dx++) {
                int src = sl + dx + 16 * dy;
                float vx0 = __shfl(x0, src);
                float vx1 = __shfl(x1, src);
                float vx2 = __shfl(x2, src);
                int wi = dy * 2 + dx;
                q0 = fmaf(p1w[wi], vx0, q0); q0 = fmaf(p1w[4 + wi],  vx1, q0); q0 = fmaf(p1w[8 + wi],  vx2, q0);
                q1 = fmaf(p1w[12 + wi], vx0, q1); q1 = fmaf(p1w[16 + wi], vx1, q1); q1 = fmaf(p1w[20 + wi], vx2, q1);
                q2 = fmaf(p1w[24 + wi], vx0, q2); q2 = fmaf(p1w[28 + wi], vx1, q2); q2 = fmaf(p1w[32 + wi], vx2, q2);
            }
        if (tl < 16) {
            int px = tl & 7, py = tl >> 3;
            unsigned op = (unsigned)(b * 3) * 16384u + (unsigned)(bandY * 2 + py) * 128u + tileX * 8 + px;
            outP1[op] = q0; outP1[op + 16384u] = q1; outP1[op + 32768u] = q2;
        }

        // ---- pool2 via shuffles ----
        int s2l = 2 * (tl & 3);
        float r0 = p2b[0], r1 = p2b[1], r2 = p2b[2];
        #pragma unroll
        for (int dy = 0; dy < 2; dy++)
            #pragma unroll
            for (int dx = 0; dx < 2; dx++) {
                int src = s2l + dx + 8 * dy;
                float vq0 = __shfl(q0, src);
                float vq1 = __shfl(q1, src);
                float vq2 = __shfl(q2, src);
                int wi = dy * 2 + dx;
                r0 = fmaf(p2w[wi], vq0, r0); r0 = fmaf(p2w[4 + wi],  vq1, r0); r0 = fmaf(p2w[8 + wi],  vq2, r0);
                r1 = fmaf(p2w[12 + wi], vq0, r1); r1 = fmaf(p2w[16 + wi], vq1, r1); r1 = fmaf(p2w[20 + wi], vq2, r1);
                r2 = fmaf(p2w[24 + wi], vq0, r2); r2 = fmaf(p2w[28 + wi], vq1, r2); r2 = fmaf(p2w[32 + wi], vq2, r2);
            }
        if (tl < 4) {
            unsigned op = (unsigned)(b * 3) * 4096u + (unsigned)bandY * 64u + tileX * 4 + tl;
            outP2[op] = r0; outP2[op + 4096u] = r1; outP2[op + 8192u] = r2;
        }
    }
}

// ---------------------------------------------------------------------------
// K1: fused ctx L2+L3 (R7 form).
// ---------------------------------------------------------------------------
__global__ __launch_bounds__(256) void k_fused23(
    const float* __restrict__ h1, float* __restrict__ outF1, float* __restrict__ outF2,
    const float* __restrict__ ctxw, const float* __restrict__ ctxb,
    const float* __restrict__ bng, const float* __restrict__ bnb)
{
    __shared__ float sx[3 * SXCH];
    __shared__ float sm[3 * H0CH];

    int t = threadIdx.x, bid = blockIdx.x;
    int tileX = bid & 3, bandY = (bid >> 2) & 15, b = bid >> 6;

    int gr0 = bandY * 16 - 3;
    int gc0 = tileX * 64 - 4;
    #pragma unroll
    for (int c = 0; c < 3; c++)
        stage19(h1 + (size_t)(b * 3 + c) * 65536, &sx[c * SXCH], gr0, gc0, 256, t);
    __syncthreads();

    {
        const float* w2c = ctxw + 162;
        float inv2[3], bb2[3];
        #pragma unroll
        for (int c = 0; c < 3; c++) { inv2[c] = bng[6 + c] / sqrtf(1.001f); bb2[c] = bnb[6 + c]; }
        #pragma unroll
        for (int p = 0; p < 2; p++) {
            int idx = t + 256 * p;
            if (idx < 297) {
                int lhy = idx / 33;
                int lhx = idx - 33 * lhy;
                bool oob = (bandY == 0 && lhy == 0) || (tileX == 0 && lhx == 0);
                float a0 = ctxb[6], a1 = ctxb[7], a2 = ctxb[8];
                #pragma unroll
                for (int c = 0; c < 3; c++) {
                    const float* basep = &sx[c * SXCH + 2 * lhy * SXSTR + 2 * lhx];
                    float inv = inv2[c], bb = bb2[c];
                    #pragma unroll
                    for (int kh = 0; kh < 3; kh++) {
                        float2 c0 = *(const float2*)(basep + kh * SXSTR);
                        float2 c1 = *(const float2*)(basep + kh * SXSTR + 2);
                        float t0 = fmaxf(fmaf(inv, c0.y, bb), 0.0f);
                        float t1 = fmaxf(fmaf(inv, c1.x, bb), 0.0f);
                        float t2 = fmaxf(fmaf(inv, c1.y, bb), 0.0f);
                        int wi = c * 9 + kh * 3;
                        a0 = fmaf(w2c[wi], t0, a0); a0 = fmaf(w2c[wi + 1], t1, a0); a0 = fmaf(w2c[wi + 2], t2, a0);
                        a1 = fmaf(w2c[27 + wi], t0, a1); a1 = fmaf(w2c[28 + wi], t1, a1); a1 = fmaf(w2c[29 + wi], t2, a1);
                        a2 = fmaf(w2c[54 + wi], t0, a2); a2 = fmaf(w2c[55 + wi], t1, a2); a2 = fmaf(w2c[56 + wi], t2, a2);
                    }
                }
                int o = lhy * H0STR + lhx;
                if (!oob && lhy >= 1 && lhx >= 1) {
                    unsigned fo = (unsigned)(b * 3) * 16384u
                                + (unsigned)(8 * bandY + lhy - 1) * 128u + 32 * tileX + lhx - 1;
                    outF1[fo] = featf(a0); outF1[fo + 16384u] = featf(a1); outF1[fo + 32768u] = featf(a2);
                }
                if (oob) { a0 = SENT; a1 = SENT; a2 = SENT; }
                sm[o] = a0; sm[H0CH + o] = a1; sm[2 * H0CH + o] = a2;
            }
        }
    }
    __syncthreads();

    if (t < 64) {
        int lx = t & 15, ly = t >> 4;
        const float* w3c = ctxw + 243;
        float a0 = ctxb[9], a1 = ctxb[10], a2 = ctxb[11];
        #pragma unroll
        for (int c = 0; c < 3; c++) {
            float inv = bng[9 + c] / sqrtf(1.001f), bb = bnb[9 + c];
            const float* mb = &sm[c * H0CH + 2 * ly * H0STR + 2 * lx];
            #pragma unroll
            for (int kh = 0; kh < 3; kh++) {
                float2 c0 = *(const float2*)(mb + kh * H0STR);
                float c2v = mb[kh * H0STR + 2];
                float t0 = fmaxf(fmaf(inv, c0.x, bb), 0.0f);
                float t1 = fmaxf(fmaf(inv, c0.y, bb), 0.0f);
                float t2 = fmaxf(fmaf(inv, c2v, bb), 0.0f);
                int wi = c * 9 + kh * 3;
                a0 = fmaf(w3c[wi], t0, a0); a0 = fmaf(w3c[wi + 1], t1, a0); a0 = fmaf(w3c[wi + 2], t2, a0);
                a1 = fmaf(w3c[27 + wi], t0, a1); a1 = fmaf(w3c[28 + wi], t1, a1); a1 = fmaf(w3c[29 + wi], t2, a1);
                a2 = fmaf(w3c[54 + wi], t0, a2); a2 = fmaf(w3c[55 + wi], t1, a2); a2 = fmaf(w3c[56 + wi], t2, a2);
            }
        }
        unsigned o = (unsigned)(b * 3) * 4096u + (unsigned)(bandY * 4 + ly) * 64u + tileX * 16 + lx;
        outF2[o] = featf(a0); outF2[o + 4096u] = featf(a1); outF2[o + 8192u] = featf(a2);
    }
}

// ---------------------------------------------------------------------------
// K2: final select + soft VQ + counts + hists -> per-block partials.
// ---------------------------------------------------------------------------
__device__ __forceinline__ int argmin8(float v, const float* __restrict__ sc) {
    float best = 1e30f; int ki = 0;
    #pragma unroll
    for (int k = 0; k < 8; k++) {
        float df = v - sc[k]; float dk = df * df;
        if (dk < best) { best = dk; ki = k; }
    }
    return ki;
}

__global__ __launch_bounds__(256) void k_final(
    const float* __restrict__ x, const float* __restrict__ f1,
    const float* __restrict__ f2, const float* __restrict__ p1,
    const float* __restrict__ p2, const float* __restrict__ thresh,
    const float* __restrict__ centers, float* __restrict__ out,
    int* __restrict__ partials)
{
    __shared__ int sh[4 * 12];
    int t = threadIdx.x;
    int lane = t & 63;
    int* shW = &sh[12 * (t >> 6)];
    if (lane < 12) shW[lane] = 0;
    float sc[8];
    #pragma unroll
    for (int k = 0; k < 8; k++) sc[k] = centers[k];
    __syncthreads();

    float th1 = thresh[0], th2 = thresh[1];
    int gid = blockIdx.x * 256 + t;
    int xc = gid & 255, y = (gid >> 8) & 255, b = gid >> 16;
    unsigned i2 = (unsigned)(((y >> 1) << 7) + (xc >> 1));
    unsigned i4 = (unsigned)(((y >> 2) << 6) + (xc >> 2));
    bool doM1 = ((y & 1) == 0) && ((xc & 1) == 0);
    bool doM2 = ((y & 3) == 0) && ((xc & 3) == 0);
    int c0n = 0, c1n = 0, c2n = 0;

    #pragma unroll
    for (int c = 0; c < 3; c++) {
        unsigned pc = (unsigned)(b * 3 + c);
        float f1v = f1[pc * 16384u + i2];
        float f2v = f2[pc * 4096u + i4];
        float p1v = p1[pc * 16384u + i2];
        float p2v = p2[pc * 4096u + i4];
        float xv  = x[pc * 65536u + (unsigned)((y << 8) + xc)];
        bool cond2 = f2v < th2;
        bool cond1 = (!cond2) && (f1v < th1);
        bool cond0 = !(cond1 || cond2);
        float xq = cond2 ? p2v : (cond1 ? p1v : xv);

        float d[8]; float dmin = 1e30f;
        #pragma unroll
        for (int k = 0; k < 8; k++) { float df = xq - sc[k]; d[k] = df * df; dmin = fminf(dmin, d[k]); }
        float se = 0.f, sn = 0.f;
        #pragma unroll
        for (int k = 0; k < 8; k++) { float e = __expf(dmin - d[k]); se += e; sn = fmaf(sc[k], e, sn); }
        out[pc * 65536u + (unsigned)((y << 8) + xc)] = sn / se;

        c0n += cond0; c1n += cond1; c2n += cond2;

        if (cond0) atomicAdd(&shW[argmin8(xv, sc)], 1);
        if (doM1 && (f2v >= th2) && (f1v < th1)) atomicAdd(&shW[argmin8(p1v, sc)], 1);
        if (doM2 && cond2) atomicAdd(&shW[argmin8(p2v, sc)], 1);
    }
    #pragma unroll
    for (int off = 32; off > 0; off >>= 1) {
        c0n += __shfl_down(c0n, off);
        c1n += __shfl_down(c1n, off);
        c2n += __shfl_down(c2n, off);
    }
    if (lane == 0) { atomicAdd(&shW[8], c0n); atomicAdd(&shW[9], c1n); atomicAdd(&shW[10], c2n); }
    __syncthreads();
    if (t < 12)
        partials[blockIdx.x * 12 + t] = sh[t] + sh[12 + t] + sh[24 + t] + sh[36 + t];
}

// ---------------------------------------------------------------------------
// K3: reduce partials [2048][12] -> scalars. 1 block, 256 threads.
// ---------------------------------------------------------------------------
__global__ void k_reduce(const int* __restrict__ partials, float* __restrict__ out2) {
    __shared__ int accs[12];
    int t = threadIdx.x;
    if (t < 12) accs[t] = 0;
    __syncthreads();
    int s[12];
    #pragma unroll
    for (int k = 0; k < 12; k++) s[k] = 0;
    for (int r = t; r < 2048; r += 256) {
        const int* row = partials + r * 12;
        #pragma unroll
        for (int k = 0; k < 12; k++) s[k] += row[k];
    }
    #pragma unroll
    for (int k = 0; k < 12; k++) {
        #pragma unroll
        for (int off = 32; off > 0; off >>= 1) s[k] += __shfl_down(s[k], off);
    }
    if ((t & 63) == 0) {
        #pragma unroll
        for (int k = 0; k < 12; k++) if (s[k]) atomicAdd(&accs[k], s[k]);
    }
    __syncthreads();
    if (t == 0) {
        float cnt0 = (float)accs[8], cnt1 = (float)accs[9], cnt2 = (float)accs[10];
        float esti = cnt0 + cnt1 * 0.25f + cnt2 * 0.0625f;
        float cr = (1.0f / 16.0f) * esti / (256.0f * 256.0f * 3.0f * 8.0f);
        float cs[8]; float tot = 0.0f;
        #pragma unroll
        for (int k = 0; k < 8; k++) { cs[k] = (float)accs[k]; tot += cs[k]; }
        float mean = 0.0f;
        #pragma unroll
        for (int k = 0; k < 8; k++) { cs[k] /= tot; mean += cs[k]; }
        mean *= 0.125f;
        float var = 0.0f;
        #pragma unroll
        for (int k = 0; k < 8; k++) { float df = cs[k] - mean; var += df * df; }
        var *= (1.0f / 7.0f);
        out2[0] = cr;
        out2[1] = sqrtf(var);
    }
}

extern "C" void kernel_launch(void* const* d_in, const int* in_sizes, int n_in,
                              void* d_out, int out_size, void* d_ws, size_t ws_size,
                              hipStream_t stream) {
    const float* x_init   = (const float*)d_in[0];
    const float* thresh   = (const float*)d_in[1];
    const float* sample_w = (const float*)d_in[2];
    const float* sample_b = (const float*)d_in[3];
    const float* centers  = (const float*)d_in[4];
    const float* pool1_w  = (const float*)d_in[5];
    const float* pool1_b  = (const float*)d_in[6];
    const float* pool2_w  = (const float*)d_in[7];
    const float* pool2_b  = (const float*)d_in[8];
    const float* ctx_w    = (const float*)d_in[9];
    const float* ctx_b    = (const float*)d_in[10];
    const float* bn_g     = (const float*)d_in[11];
    const float* bn_b     = (const float*)d_in[12];
    float* out = (float*)d_out;

    float* wsf      = (float*)d_ws;
    int*   partials = (int*)wsf;               // [2048][12] ints
    float* bufX     = wsf + 32768;             // [8,3,256,256]
    float* bufH1    = bufX  + 1572864;         // [8,3,256,256]
    float* bufP1    = bufH1 + 1572864;         // [8,3,128,128]
    float* bufP2    = bufP1 + 393216;          // [8,3,64,64]
    float* bufF1    = bufP2 + 98304;           // [8,3,128,128]
    float* bufF2    = bufF1 + 393216;          // [8,3,64,64]

    k_fused01<<<8192, 256, 0, stream>>>(x_init, sample_w, sample_b,
                                        ctx_w, ctx_b, bn_g, bn_b,
                                        pool1_w, pool1_b, pool2_w, pool2_b,
                                        bufX, bufH1, bufP1, bufP2);
    k_fused23<<<512, 256, 0, stream>>>(bufH1, bufF1, bufF2,
                                       ctx_w, ctx_b, bn_g, bn_b);
    k_final<<<2048, 256, 0, stream>>>(bufX, bufF1, bufF2, bufP1, bufP2,
                                      thresh, centers, out, partials);
    k_reduce<<<1, 256, 0, stream>>>(partials, out + 1572864);
}